// Round 6
// baseline (310.708 us; speedup 1.0000x reference)
//
#include <hip/hip_runtime.h>
#include <math.h>

// Problem constants
#define B_    128
#define T_    2048
#define DIN   128
#define HID_  132
#define DOUT  64

// Tiling
#define TC    128            // time-steps per fused block
#define NCC   (T_ / TC)      // 16 chunks
#define AS    168            // act row stride (f16): 336B, 16B-aligned, best conflict class
#define WBUF  9216           // one wt buffer: 144 rows x 64 f16 = 18432 B

typedef _Float16 half8   __attribute__((ext_vector_type(8)));
typedef _Float16 half4v  __attribute__((ext_vector_type(4)));
typedef float    float4v __attribute__((ext_vector_type(4)));

__device__ __forceinline__ float4v max4(float4v a, float4v b) {
    float4v r;
#pragma unroll
    for (int i = 0; i < 4; ++i) r[i] = fmaxf(a[i], b[i]);
    return r;
}

// ---------------------------------------------------------------------------
// global -> LDS direct DMA, 16B/lane, contiguous 1KB per wave-instruction.
// bytes must be a multiple of 1024. Instr i of wave w covers [w*1024 + i*4096).
// ---------------------------------------------------------------------------
__device__ __forceinline__ void dma_chunk(const _Float16* __restrict__ src,
                                          _Float16* dst, int bytes, int tid) {
    const int w = tid >> 6, lane = tid & 63;
    for (int off = w * 1024; off < bytes; off += 4096) {
        const char* g = (const char*)src + off + lane * 16;
        char*       l = (char*)dst + off + lane * 16;
        __builtin_amdgcn_global_load_lds(
            (const __attribute__((address_space(1))) unsigned int*)g,
            (__attribute__((address_space(3))) unsigned int*)l, 16, 0, 0);
    }
}

// ---------------------------------------------------------------------------
// Kernel 1: blocks [0,32): weight prep into DMA-swizzled layout.
//           blocks [32, 32+2048): per-chunk column max of P (float4 loads).
// Swizzle (per layer, rows R, padded K = KP): element (k, n) lives at
//   ci=k/64, kr=k%64, kc=min(64,KP-64ci), g=kr/8, j=kr%8, h=g/4, q=g%4
//   off = ci*R*64 + (n/16)*16*kc + h*512 + q*128 + (n%16)*8 + j
// so one 64-k chunk is lane-contiguous in exactly MFMA fragment order.
// ---------------------------------------------------------------------------
__global__ __launch_bounds__(256) void prep_chunkmax_kernel(
    const float* __restrict__ P,
    const float* __restrict__ W1, const float* __restrict__ b1,
    const float* __restrict__ W2, const float* __restrict__ b2,
    const float* __restrict__ W3, const float* __restrict__ b3,
    const float* __restrict__ W4, const float* __restrict__ b4,
    float* __restrict__ cmax,
    _Float16* __restrict__ SW1, _Float16* __restrict__ SW2,
    _Float16* __restrict__ SW3, _Float16* __restrict__ SW4,
    float* __restrict__ bpad) {
    const int bid = blockIdx.x;
    const int tid = threadIdx.x;
    if (bid >= 32) {
        // ---- chunk max: (c4 0..31 covering d) x (sg 0..7 t-segments) ----
        __shared__ float4v smax1[256];
        const int cb = bid - 32;
        const int b = cb >> 4, c = cb & 15;
        const int c4 = tid & 31, sg = tid >> 5;
        const float* p = P + ((size_t)(b * T_ + c * TC + sg * 16)) * DIN + c4 * 4;
        float4v m = {-INFINITY, -INFINITY, -INFINITY, -INFINITY};
#pragma unroll
        for (int i = 0; i < 16; ++i)
            m = max4(m, *(const float4v*)(p + (size_t)i * DIN));
        smax1[sg * 32 + c4] = m;
        __syncthreads();
        if (tid < 32) {
            float4v r = smax1[tid];
#pragma unroll
            for (int s = 1; s < 8; ++s) r = max4(r, smax1[s * 32 + tid]);
            *(float4v*)(cmax + ((size_t)b * NCC + c) * DIN + tid * 4) = r;
        }
    } else {
        // ---- weight prep: 8 slice-blocks per layer, coalesced row reads ----
        const int l = bid >> 3, slice = bid & 7;
        const float *W, *bs; _Float16* dst; int K, N, KP, R, NB;
        if (l == 0)      { W = W1; bs = b1; dst = SW1; K = 128; N = 132; KP = 128; R = 144; NB = 132; }
        else if (l == 1) { W = W2; bs = b2; dst = SW2; K = 132; N = 132; KP = 160; R = 144; NB = 132; }
        else if (l == 2) { W = W3; bs = b3; dst = SW3; K = 132; N = 132; KP = 160; R = 144; NB = 132; }
        else             { W = W4; bs = b4; dst = SW4; K = 132; N = 64;  KP = 160; R = 64;  NB = 64;  }
        for (int k = slice; k < KP; k += 8) {
            const int ci = k >> 6, kr = k & 63;
            const int kc = (KP - (ci << 6) < 64) ? 32 : 64;
            const int g = kr >> 3, j = kr & 7, h = g >> 2, q = g & 3;
            for (int n = tid; n < R; n += 256) {
                float v = (k < K && n < N) ? W[(size_t)k * N + n] : 0.f;
                size_t off = (size_t)ci * R * 64 + (size_t)(n >> 4) * 16 * kc +
                             h * 512 + q * 128 + (n & 15) * 8 + j;
                dst[off] = (_Float16)v;
            }
        }
        if (slice == 0)
            for (int i = tid; i < 144; i += 256)
                bpad[l * 144 + i] = (i < NB) ? bs[i] : 0.f;
    }
}

// ---------------------------------------------------------------------------
// One MLP layer via 16x16x32 f16 MFMA, swapped operands (D = W x act -> D^T).
// 2x2 wave split: wave (mh,jh) owns rows [64*mh, 64*mh+64) as 4 strips of 16
// and n-tiles with parity jh (5/4 for NT=9). Per kt: 4 a-reads + <=5 w-reads
// feed <=20 MFMAs (vs 11 reads / 18 MFMA with the 1x4 split) -> 23% less LDS.
// Weight chunks double-buffered via global_load_lds: chunk i+1's DMA issues
// AFTER the barrier gating compute(i), so its latency hides under compute(i).
// PAR = buffer index of this layer's chunk 0; NEXTB = next layer chunk0 bytes.
// ---------------------------------------------------------------------------
template <int NT, int KTOT, bool LAST, int PAR, int NEXTB>
__device__ __forceinline__ void mlp_layer(const _Float16* __restrict__ Wsw,
                                          const float* __restrict__ bp,
                                          _Float16* act, _Float16* wtA, _Float16* wtB,
                                          float* __restrict__ outg, int tid,
                                          const _Float16* __restrict__ Wnext) {
    const int wave = tid >> 6, lane = tid & 63;
    const int quad = lane >> 4, l16 = lane & 15;
    const int mh = wave >> 1, jh = wave & 1;
    constexpr int NCH = (KTOT + 63) / 64;
    constexpr int UMAX = (NT + 1) / 2;
    float4v C[4][UMAX];
#pragma unroll
    for (int s = 0; s < 4; ++s)
#pragma unroll
        for (int u = 0; u < UMAX; ++u) C[s][u] = (float4v)0.0f;

    const int r0 = 64 * mh + l16;
#pragma unroll
    for (int ci = 0; ci < NCH; ++ci) {
        const int kb = ci * 64;
        const int kc = (KTOT - kb < 64) ? 32 : 64;
        _Float16* cur = ((PAR + ci) & 1) ? wtB : wtA;
        _Float16* nxt = ((PAR + ci) & 1) ? wtA : wtB;
        __syncthreads();   // drains chunk-ci DMA (in flight since last barrier)
        if (ci + 1 < NCH) {
            const int nb = (KTOT - (kb + 64) < 64) ? NT * 16 * 32 * 2 : NT * 16 * 64 * 2;
            dma_chunk(Wsw + (size_t)(kb + 64) * (NT * 16), nxt, nb, tid);
        } else if (!LAST) {
            dma_chunk(Wnext, nxt, NEXTB, tid);
        }
#pragma unroll
        for (int kt = 0; kt < kc; kt += 32) {
            const int ko = kb + kt + quad * 8;
            half8 a[4];
#pragma unroll
            for (int s = 0; s < 4; ++s)
                a[s] = *(const half8*)(act + (size_t)(r0 + 16 * s) * AS + ko);
            const _Float16* wb = cur + (kt >> 5) * 512 + quad * 128 + l16 * 8;
#pragma unroll
            for (int u = 0; u < UMAX; ++u) {
                const int nt = jh + 2 * u;
                if (nt < NT) {
                    half8 w = *(const half8*)(wb + nt * 16 * kc);
#pragma unroll
                    for (int s = 0; s < 4; ++s)
                        C[s][u] = __builtin_amdgcn_mfma_f32_16x16x32_f16(w, a[s], C[s][u], 0, 0, 0);
                }
            }
        }
    }
    if (!LAST) __syncthreads();   // all act reads done before in-place overwrite
#pragma unroll
    for (int s = 0; s < 4; ++s) {
        const int m = 64 * mh + 16 * s + l16;
#pragma unroll
        for (int u = 0; u < UMAX; ++u) {
            const int nt = jh + 2 * u;
            if (nt < NT) {
                const int n0 = nt * 16 + quad * 4;
                float4v c = C[s][u];
                float4v bv = *(const float4v*)(bp + n0);
                if (LAST) {
                    float4v o;
#pragma unroll
                    for (int r = 0; r < 4; ++r)
                        o[r] = 1.f / (1.f + __expf(-5.f * (c[r] + bv[r])));
                    *(float4v*)(outg + (size_t)m * DOUT + n0) = o;
                } else {
                    half4v hv;
#pragma unroll
                    for (int r = 0; r < 4; ++r)
                        hv[r] = (_Float16)fmaxf(c[r] + bv[r], 0.f);
                    *(half4v*)(act + (size_t)m * AS + n0) = hv;
                }
            }
        }
    }
    // next layer's first __syncthreads() orders these writes vs. its reads
}

// ---------------------------------------------------------------------------
// Fused kernel: reverse cummax (16 parallel segments of 8, b128 stores)
// -> 4 MFMA layers
// ---------------------------------------------------------------------------
__global__ __launch_bounds__(256, 2) void fused_kernel(
    const float* __restrict__ P, const float* __restrict__ cmax,
    const _Float16* __restrict__ SW1, const _Float16* __restrict__ SW2,
    const _Float16* __restrict__ SW3, const _Float16* __restrict__ SW4,
    const float* __restrict__ bpad, float* __restrict__ Out) {
    __shared__ __align__(16) _Float16 act[TC * AS];      // 43008 B
    __shared__ __align__(16) _Float16 wtbuf[2 * WBUF];   // 36864 B (total 79872 -> 2 blk/CU)
    _Float16* wtA = wtbuf;
    _Float16* wtB = wtbuf + WBUF;

    const int bid = blockIdx.x;
    const int b = bid / NCC, c = bid % NCC;
    const int tid = threadIdx.x;

    // layer-1 chunk-0 weight DMA flies under the whole cummax phase (-> wtA)
    dma_chunk(SW1, wtA, 144 * 64 * 2, tid);

    {   // zero K-pad cols [144,160) (read as A-operand by layers 2-4)
        const int m = tid >> 1, s2 = tid & 1;
        uint4 z{0, 0, 0, 0};
        *(uint4*)(act + (size_t)m * AS + 144 + s2 * 8) = z;
    }
    {   // reverse cummax: 16 parallel t-segments of 8, 8 f32 cols/thread,
        // half8 (b128) LDS stores. smax aliases wtB (idle until chunk-1 DMA,
        // which is issued only after mlp_layer's first barrier).
        float4v* smax = (float4v*)wtB;   // [16 seg][16 c8][2]
        const int c8 = tid & 15, sg = tid >> 4;
        const float* p = P + ((size_t)(b * T_ + c * TC + sg * 8)) * DIN + c8 * 8;
        float4v r0v = {-INFINITY, -INFINITY, -INFINITY, -INFINITY};
        float4v r1v = r0v;
#pragma unroll
        for (int i = 7; i >= 0; --i) {
            r0v = max4(r0v, *(const float4v*)(p + (size_t)i * DIN));
            r1v = max4(r1v, *(const float4v*)(p + (size_t)i * DIN + 4));
            half8 h;
#pragma unroll
            for (int j = 0; j < 4; ++j) { h[j] = (_Float16)r0v[j]; h[4 + j] = (_Float16)r1v[j]; }
            *(half8*)(act + (size_t)(sg * 8 + i) * AS + c8 * 8) = h;
        }
        smax[(sg * 16 + c8) * 2]     = r0v;
        smax[(sg * 16 + c8) * 2 + 1] = r1v;
        __syncthreads();
        // tail = max over later chunks (cmax) + later segments; fold into own rows
        float4v t0 = {-INFINITY, -INFINITY, -INFINITY, -INFINITY};
        float4v t1 = t0;
        for (int j = c + 1; j < NCC; ++j) {
            const float* cm = cmax + ((size_t)b * NCC + j) * DIN + c8 * 8;
            t0 = max4(t0, *(const float4v*)cm);
            t1 = max4(t1, *(const float4v*)(cm + 4));
        }
        for (int s = sg + 1; s < 16; ++s) {
            t0 = max4(t0, smax[(s * 16 + c8) * 2]);
            t1 = max4(t1, smax[(s * 16 + c8) * 2 + 1]);
        }
        half8 tl;
#pragma unroll
        for (int j = 0; j < 4; ++j) { tl[j] = (_Float16)t0[j]; tl[4 + j] = (_Float16)t1[j]; }
#pragma unroll
        for (int i = 0; i < 8; ++i) {
            _Float16* a = act + (size_t)(sg * 8 + i) * AS + c8 * 8;
            half8 v = *(half8*)a;
            half8 r;
#pragma unroll
            for (int j = 0; j < 8; ++j) r[j] = (v[j] > tl[j]) ? v[j] : tl[j];
            *(half8*)a = r;
        }
        // mlp_layer's first __syncthreads() orders these vs. fragment reads
    }

    float* outg = Out + (size_t)(b * T_ + c * TC) * DOUT;
    mlp_layer<9, 128, false, 0, 18432>(SW1, bpad,       act, wtA, wtB, nullptr, tid, SW2);
    mlp_layer<9, 160, false, 0, 18432>(SW2, bpad + 144, act, wtA, wtB, nullptr, tid, SW3);
    mlp_layer<9, 160, false, 1, 8192 >(SW3, bpad + 288, act, wtA, wtB, nullptr, tid, SW4);
    mlp_layer<4, 160, true,  0, 0    >(SW4, bpad + 432, act, wtA, wtB, outg,    tid, nullptr);
}

// ---------------------------------------------------------------------------
extern "C" void kernel_launch(void* const* d_in, const int* in_sizes, int n_in,
                              void* d_out, int out_size, void* d_ws, size_t ws_size,
                              hipStream_t stream) {
    const float* P  = (const float*)d_in[0];
    const float* W1 = (const float*)d_in[1];
    const float* b1 = (const float*)d_in[2];
    const float* W2 = (const float*)d_in[3];
    const float* b2 = (const float*)d_in[4];
    const float* W3 = (const float*)d_in[5];
    const float* b3 = (const float*)d_in[6];
    const float* W4 = (const float*)d_in[7];
    const float* b4 = (const float*)d_in[8];
    float* out = (float*)d_out;

    // ws layout
    char* ws = (char*)d_ws;
    float*    cmax = (float*)ws;                          // 1 MiB
    _Float16* SW1  = (_Float16*)(ws + (1 << 20));         // 144*128 f16 (swizzled)
    _Float16* SW2  = SW1 + 144 * 128;                     // 144*160
    _Float16* SW3  = SW2 + 144 * 160;                     // 144*160
    _Float16* SW4  = SW3 + 144 * 160;                     // 64*160
    float*    bpad = (float*)(SW4 + 64 * 160);            // 4*144 f32

    prep_chunkmax_kernel<<<B_ * NCC + 32, 256, 0, stream>>>(
        P, W1, b1, W2, b2, W3, b3, W4, b4, cmax, SW1, SW2, SW3, SW4, bpad);
    fused_kernel<<<B_ * NCC, 256, 0, stream>>>(P, cmax, SW1, SW2, SW3, SW4,
                                               bpad, out);
}